// Round 3
// baseline (226.735 us; speedup 1.0000x reference)
//
#include <hip/hip_runtime.h>
#include <hip/hip_bf16.h>
#include <cstdint>
#include <cstddef>

#define BATCH 8192
#define IDIM  768
#define JDIM  768
#define GRID  5
#define KDIM  (IDIM * GRID)   // 3840

// ---------------- helpers ----------------

__device__ __forceinline__ unsigned short f2bf(float f) {
    unsigned int u = __float_as_uint(f);
    u += 0x7fffu + ((u >> 16) & 1u);
    return (unsigned short)(u >> 16);
}

typedef __bf16 bf16x8 __attribute__((ext_vector_type(8)));
typedef float  f32x16 __attribute__((ext_vector_type(16)));
typedef unsigned short ushortx4 __attribute__((ext_vector_type(4)));

__device__ __forceinline__ void async_copy16(const void* gsrc, void* ldsdst) {
    __builtin_amdgcn_global_load_lds(
        (const __attribute__((address_space(1))) unsigned int*)gsrc,
        (__attribute__((address_space(3))) unsigned int*)ldsdst,
        16, 0, 0);
}

// ---------------- fused precompute: basis + Wt + bias in ONE dispatch ----------
// Block ranges:
//   [0, NBAS)                : Abas[b][g*768+i] = bf16(exp(-5*(tanh(x)-grid_g)^2))
//   [NBAS, NBAS+NWT)         : Wt[j][g*768+i] = bf16(coeffs[i,j,g]*scale[i,j])
//   [NBAS+NWT, +NBIAS)       : bias[j] = sum_i shift[i,j]   (no atomics)

#define WT_I 32
#define WT_J 64
#define NBAS  ((BATCH * (IDIM / 4)) / 256)          // 6144
#define NWT   ((IDIM / WT_I) * (JDIM / WT_J))       // 288
#define NBIAS (JDIM / 64)                           // 12

__global__ __launch_bounds__(256)
void precompute_kernel(const float* __restrict__ x,
                       const float* __restrict__ coeffs,
                       const float* __restrict__ scale,
                       const float* __restrict__ shift,
                       unsigned short* __restrict__ Wt,
                       float* __restrict__ bias,
                       unsigned short* __restrict__ Abas) {
    const int blk = blockIdx.x;
    const int t   = threadIdx.x;

    if (blk < NBAS) {
        // ---- basis ----
        const int idx = blk * 256 + t;
        const int b  = idx / (IDIM / 4);
        const int i4 = (idx - b * (IDIM / 4)) * 4;
        const float4 xv = *(const float4*)&x[(size_t)b * IDIM + i4];
        const float xs[4] = {xv.x, xv.y, xv.z, xv.w};
        float tv[4];
#pragma unroll
        for (int u = 0; u < 4; ++u) {
            const float e = __expf(2.f * xs[u]);     // tanh via exp, saturates ok
            tv[u] = 1.f - 2.f / (e + 1.f);
        }
#pragma unroll
        for (int g = 0; g < GRID; ++g) {
            const float gv = -1.f + 0.5f * (float)g;
            ushortx4 o;
#pragma unroll
            for (int u = 0; u < 4; ++u) {
                const float d = tv[u] - gv;
                o[u] = f2bf(__expf(-5.f * d * d));
            }
            *(ushortx4*)&Abas[(size_t)b * KDIM + g * IDIM + i4] = o;
        }
    } else if (blk < NBAS + NWT) {
        // ---- Wt (LDS transpose: coalesced read over j, coalesced write over i) ----
        __shared__ __align__(16) unsigned short tile[GRID][WT_J][WT_I + 4];
        const int wblk = blk - NBAS;
        const int i0 = (wblk / (JDIM / WT_J)) * WT_I;
        const int j0 = (wblk % (JDIM / WT_J)) * WT_J;
        const int jj = t & 63;
#pragma unroll
        for (int it = 0; it < (WT_I * WT_J) / 256; ++it) {     // 8 iters
            const int ii = it * 4 + (t >> 6);
            const int i = i0 + ii, j = j0 + jj;
            const float* cp = &coeffs[((size_t)i * JDIM + j) * GRID];
            const float  sc = scale[(size_t)i * JDIM + j];
#pragma unroll
            for (int g = 0; g < GRID; ++g)
                tile[g][jj][ii] = f2bf(cp[g] * sc);
        }
        __syncthreads();
#pragma unroll
        for (int it = 0; it < (WT_J * GRID * (WT_I / 4)) / 256; ++it) { // 10 iters
            const int p  = it * 256 + t;
            const int iq = p & 7;
            const int q  = p >> 3;
            const int g  = q % GRID;
            const int j  = q / GRID;
            ushortx4 v = *(const ushortx4*)&tile[g][j][iq * 4];
            *(ushortx4*)&Wt[(size_t)(j0 + j) * KDIM + g * IDIM + i0 + iq * 4] = v;
        }
    } else {
        // ---- bias: 12 blocks, each does 64 j's over all 768 i's ----
        __shared__ float red[4][64];
        const int j0 = (blk - NBAS - NWT) * 64;
        const int jj = t & 63;
        const int ip = t >> 6;
        float s = 0.f;
        for (int i = ip; i < IDIM; i += 4)
            s += shift[(size_t)i * JDIM + j0 + jj];
        red[ip][jj] = s;
        __syncthreads();
        if (t < 64)
            bias[j0 + t] = red[0][t] + red[1][t] + red[2][t] + red[3][t];
    }
}

// ---------------- MFMA GEMM v3 ----------------
// C[8192,768] = Abas @ Wt^T + bias.  32x32x16 MFMA.
// BM=128, BN=64, BK=128. Grid = 12 x 64 = 768 blocks = exactly 3/CU.
// LDS = 48 KB/block (x3 = 144 KB/CU). XOR chunk swizzle (measured 0 conflicts).

#define BM 128
#define BN 64
#define BK 128

__global__ __launch_bounds__(256, 3)
void kan_gemm(const unsigned short* __restrict__ Abas,  // [BATCH][KDIM]
              const unsigned short* __restrict__ Wt,    // [JDIM][KDIM]
              const float* __restrict__ bias,           // [JDIM]
              float* __restrict__ out) {                // [BATCH][JDIM]
    __shared__ unsigned short As[BM * BK];  // 32 KB
    __shared__ unsigned short Bs[BN * BK];  // 16 KB

    const int t    = threadIdx.x;
    const int lane = t & 63;
    const int wave = t >> 6;
    const int m0 = blockIdx.y * BM;
    const int n0 = blockIdx.x * BN;
    const int wm = (wave >> 1) * 64;   // 0 / 64
    const int wn = (wave & 1) * 32;    // 0 / 32

    f32x16 acc[2] = {};                // fm=0,1 -> m = wm + fm*32

    // staging: 256 threads x 16B = 4 KB = 16 rows of 256 B per issue-round.
    // LDS slot (row, chunk lc) holds global chunk cg = lc ^ (row&7).
    const int lrow = t >> 4;          // 0..15
    const int lc   = t & 15;          // chunk 0..15 (16B chunks, 8 elems)
    const int cg   = lc ^ (lrow & 7);
    const int ldsoff = lrow * BK + lc * 8;
    const size_t abase = (size_t)(m0 + lrow) * KDIM + cg * 8;
    const size_t bbase = (size_t)(n0 + lrow) * KDIM + cg * 8;

    const int mrow = lane & 31;        // fragment row (m or n)
    const int khalf = lane >> 5;       // 0/1 -> k-offset 0/8 inside 16

    for (int kt = 0; kt < KDIM; kt += BK) {
#pragma unroll
        for (int s = 0; s < 8; ++s)    // A: 128 rows
            async_copy16(&Abas[abase + (size_t)(16 * s) * KDIM + kt], &As[ldsoff + 16 * s * BK]);
#pragma unroll
        for (int s = 0; s < 4; ++s)    // B: 64 rows
            async_copy16(&Wt[bbase + (size_t)(16 * s) * KDIM + kt], &Bs[ldsoff + 16 * s * BK]);
        asm volatile("s_waitcnt vmcnt(0)" ::: "memory");
        __syncthreads();

#pragma unroll
        for (int ks = 0; ks < 8; ++ks) {          // 8 k16-steps
            // logical 16B chunk: c = ks*2 + khalf; swizzled slot:
            const int pc = (ks * 2 + khalf) ^ (lane & 7);
            bf16x8 a0 = *(const bf16x8*)&As[(wm +      mrow) * BK + pc * 8];
            bf16x8 a1 = *(const bf16x8*)&As[(wm + 32 + mrow) * BK + pc * 8];
            bf16x8 b0 = *(const bf16x8*)&Bs[(wn +      mrow) * BK + pc * 8];
            acc[0] = __builtin_amdgcn_mfma_f32_32x32x16_bf16(a0, b0, acc[0], 0, 0, 0);
            acc[1] = __builtin_amdgcn_mfma_f32_32x32x16_bf16(a1, b0, acc[1], 0, 0, 0);
        }
        __syncthreads();
    }

    // epilogue: 32x32 D mapping col=lane&31, row=(reg&3)+8*(reg>>2)+4*(lane>>5)
    // [measured m74/m101]
    const int j  = n0 + wn + (lane & 31);
    const float bj = bias[j];
    const int rb = 4 * (lane >> 5);
#pragma unroll
    for (int fm = 0; fm < 2; ++fm) {
#pragma unroll
        for (int reg = 0; reg < 16; ++reg) {
            const int row = m0 + wm + fm * 32 + (reg & 3) + 8 * (reg >> 2) + rb;
            out[(size_t)row * JDIM + j] = acc[fm][reg] + bj;
        }
    }
}

// ---------------- fallback (ws too small): slow but correct ----------------

__global__ __launch_bounds__(256)
void fallback_kernel(const float* __restrict__ x,
                     const float* __restrict__ coeffs,
                     const float* __restrict__ scale,
                     const float* __restrict__ shift,
                     float* __restrict__ out) {
    __shared__ float bas[KDIM];
    const int b = blockIdx.x;
    const int t = threadIdx.x;
    for (int i = t; i < IDIM; i += 256) {
        float tv = tanhf(x[(size_t)b * IDIM + i]);
#pragma unroll
        for (int g = 0; g < GRID; ++g) {
            float d = tv - (-1.0f + 0.5f * (float)g);
            bas[g * IDIM + i] = __expf(-5.0f * d * d);
        }
    }
    __syncthreads();
#pragma unroll
    for (int jj = 0; jj < 3; ++jj) {
        const int j = t + jj * 256;
        float acc = 0.f;
        for (int i = 0; i < IDIM; ++i) {
            const float sc = scale[(size_t)i * JDIM + j];
            const float* cp = &coeffs[((size_t)i * JDIM + j) * GRID];
            float s5 = 0.f;
#pragma unroll
            for (int g = 0; g < GRID; ++g) s5 += bas[g * IDIM + i] * cp[g];
            acc += s5 * sc + shift[(size_t)i * JDIM + j];
        }
        out[(size_t)b * JDIM + j] = acc;
    }
}

// ---------------- launch ----------------

extern "C" void kernel_launch(void* const* d_in, const int* in_sizes, int n_in,
                              void* d_out, int out_size, void* d_ws, size_t ws_size,
                              hipStream_t stream) {
    const float* x      = (const float*)d_in[0];
    const float* coeffs = (const float*)d_in[1];
    const float* scale  = (const float*)d_in[2];
    const float* shift  = (const float*)d_in[3];
    float* out = (float*)d_out;

    const size_t wt_bytes   = (size_t)JDIM * KDIM * sizeof(unsigned short); // 5,898,240
    const size_t bias_off   = wt_bytes;
    const size_t bias_bytes = (size_t)JDIM * sizeof(float);
    const size_t bas_off    = bias_off + bias_bytes;
    const size_t bas_bytes  = (size_t)BATCH * KDIM * sizeof(unsigned short);
    const size_t need       = bas_off + bas_bytes;                          // ~68.8 MB

    if (ws_size >= need) {
        unsigned short* Wt   = (unsigned short*)d_ws;
        float*          bias = (float*)((char*)d_ws + bias_off);
        unsigned short* Abas = (unsigned short*)((char*)d_ws + bas_off);

        precompute_kernel<<<NBAS + NWT + NBIAS, 256, 0, stream>>>(
            x, coeffs, scale, shift, Wt, bias, Abas);
        kan_gemm<<<dim3(JDIM / BN, BATCH / BM), 256, 0, stream>>>(Abas, Wt, bias, out);
    } else {
        fallback_kernel<<<BATCH, 256, 0, stream>>>(x, coeffs, scale, shift, out);
    }
}

// Round 4
// 226.310 us; speedup vs baseline: 1.0019x; 1.0019x over previous
//
#include <hip/hip_runtime.h>
#include <hip/hip_bf16.h>
#include <cstdint>
#include <cstddef>

#define BATCH 8192
#define IDIM  768
#define JDIM  768
#define GRID  5
#define KDIM  (IDIM * GRID)   // 3840

// ---------------- helpers ----------------

__device__ __forceinline__ unsigned short f2bf(float f) {
    unsigned int u = __float_as_uint(f);
    u += 0x7fffu + ((u >> 16) & 1u);
    return (unsigned short)(u >> 16);
}

typedef __bf16 bf16x8 __attribute__((ext_vector_type(8)));
typedef float  f32x4  __attribute__((ext_vector_type(4)));
typedef unsigned short ushortx4 __attribute__((ext_vector_type(4)));
typedef unsigned short ushortx8 __attribute__((ext_vector_type(8)));

__device__ __forceinline__ void async_copy16(const void* gsrc, void* ldsdst) {
    __builtin_amdgcn_global_load_lds(
        (const __attribute__((address_space(1))) unsigned int*)gsrc,
        (__attribute__((address_space(3))) unsigned int*)ldsdst,
        16, 0, 0);
}

// ---------------- basis v3: no LDS, 8 elems/thread, factorized exp ----------
// exp(-5(t-g)^2) = exp(-5t^2) * exp(-5g^2) * exp(5t)^(2g),  g in {-1,-.5,0,.5,1}
// => u = exp(-5t^2), E = exp(5t), Ei = rcp(E):
//    b(-1)=u*C1*Ei^2, b(-.5)=u*C2*Ei, b(0)=u, b(.5)=u*C2*E, b(1)=u*C1*E^2
// C1 = e^-5, C2 = e^-1.25.  tanh via exp + rcp (saturates correctly).

#define BPT 8   // elems per thread; grid = 8192*96/256 = 3072 blocks

__global__ __launch_bounds__(256)
void basis_kernel(const float* __restrict__ x, unsigned short* __restrict__ Abas) {
    const int idx = blockIdx.x * 256 + threadIdx.x;
    const int b  = idx / (IDIM / BPT);                 // /96
    const int i0 = (idx - b * (IDIM / BPT)) * BPT;
    const float4 x0 = *(const float4*)&x[(size_t)b * IDIM + i0];
    const float4 x1 = *(const float4*)&x[(size_t)b * IDIM + i0 + 4];
    const float xs[8] = {x0.x, x0.y, x0.z, x0.w, x1.x, x1.y, x1.z, x1.w};

    const float C1 = 6.7379469990854670966e-3f;   // e^-5
    const float C2 = 0.28650479686019010032f;     // e^-1.25

    ushortx8 o0, o1, o2, o3, o4;
#pragma unroll
    for (int e = 0; e < 8; ++e) {
        const float e2 = __expf(2.f * xs[e]);
        const float t  = 1.f - 2.f * __builtin_amdgcn_rcpf(e2 + 1.f);
        const float u  = __expf(-5.f * t * t);
        const float E  = __expf(5.f * t);
        const float Ei = __builtin_amdgcn_rcpf(E);
        const float m1 = u * C1, m2 = u * C2;
        o0[e] = f2bf(m1 * Ei * Ei);
        o1[e] = f2bf(m2 * Ei);
        o2[e] = f2bf(u);
        o3[e] = f2bf(m2 * E);
        o4[e] = f2bf(m1 * E * E);
    }
    unsigned short* p = &Abas[(size_t)b * KDIM + i0];
    *(ushortx8*)&p[0 * IDIM] = o0;
    *(ushortx8*)&p[1 * IDIM] = o1;
    *(ushortx8*)&p[2 * IDIM] = o2;
    *(ushortx8*)&p[3 * IDIM] = o3;
    *(ushortx8*)&p[4 * IDIM] = o4;
}

// ---------------- Wt + bias (300 blocks, one dispatch) ----------------

#define WT_I 32
#define WT_J 64
#define NWT   ((IDIM / WT_I) * (JDIM / WT_J))       // 288
#define NBIAS (JDIM / 64)                           // 12

__global__ __launch_bounds__(256)
void wtbias_kernel(const float* __restrict__ coeffs,
                   const float* __restrict__ scale,
                   const float* __restrict__ shift,
                   unsigned short* __restrict__ Wt,
                   float* __restrict__ bias) {
    __shared__ __align__(16) unsigned short tile[GRID][WT_J][WT_I + 4];
    __shared__ float red[4][64];
    const int blk = blockIdx.x;
    const int t   = threadIdx.x;

    if (blk < NWT) {
        const int i0 = (blk / (JDIM / WT_J)) * WT_I;
        const int j0 = (blk % (JDIM / WT_J)) * WT_J;
        const int jj = t & 63;
#pragma unroll
        for (int it = 0; it < (WT_I * WT_J) / 256; ++it) {     // 8 iters
            const int ii = it * 4 + (t >> 6);
            const int i = i0 + ii, j = j0 + jj;
            const float* cp = &coeffs[((size_t)i * JDIM + j) * GRID];
            const float  sc = scale[(size_t)i * JDIM + j];
#pragma unroll
            for (int g = 0; g < GRID; ++g)
                tile[g][jj][ii] = f2bf(cp[g] * sc);
        }
        __syncthreads();
#pragma unroll
        for (int it = 0; it < (WT_J * GRID * (WT_I / 4)) / 256; ++it) { // 10 iters
            const int p  = it * 256 + t;
            const int iq = p & 7;
            const int q  = p >> 3;
            const int g  = q % GRID;
            const int j  = q / GRID;
            ushortx4 v = *(const ushortx4*)&tile[g][j][iq * 4];
            *(ushortx4*)&Wt[(size_t)(j0 + j) * KDIM + g * IDIM + i0 + iq * 4] = v;
        }
    } else {
        const int j0 = (blk - NWT) * 64;
        const int jj = t & 63;
        const int ip = t >> 6;
        float s = 0.f;
        for (int i = ip; i < IDIM; i += 4)
            s += shift[(size_t)i * JDIM + j0 + jj];
        red[ip][jj] = s;
        __syncthreads();
        if (t < 64)
            bias[j0 + t] = red[0][t] + red[1][t] + red[2][t] + red[3][t];
    }
}

// ---------------- MFMA GEMM v4: 16x16x32, double-buffered LDS ----------------
// BM=128, BN=128, BK=64. Grid 6x64 = 384. LDS = 2*(16+16) KB = 64 KB.
// Stage tile k+1 into the other buffer BEFORE computing tile k -> the
// end-of-iter vmcnt(0) finds loads already landed (drain hidden).
// XOR k-chunk swizzle (measured 0 conflicts for the 16x16 pattern, r2).

#define BM 128
#define BN 128
#define BK 64

__global__ __launch_bounds__(256, 2)
void kan_gemm(const unsigned short* __restrict__ Abas,  // [BATCH][KDIM]
              const unsigned short* __restrict__ Wt,    // [JDIM][KDIM]
              const float* __restrict__ bias,           // [JDIM]
              float* __restrict__ out) {                // [BATCH][JDIM]
    __shared__ unsigned short As[2][BM * BK];  // 2 x 16 KB
    __shared__ unsigned short Bs[2][BN * BK];  // 2 x 16 KB

    const int t    = threadIdx.x;
    const int lane = t & 63;
    const int wave = t >> 6;
    const int m0 = blockIdx.y * BM;
    const int n0 = blockIdx.x * BN;
    const int wm = (wave >> 1) * 64;
    const int wn = (wave & 1) * 64;

    f32x4 acc[4][4] = {};

    // staging: thread t -> LDS slot (row=t>>3, chunk lc=t&7); slot holds
    // global chunk cg = lc ^ (row&7).
    const int lrow = t >> 3;
    const int lc   = t & 7;
    const int cg   = lc ^ (lrow & 7);
    const int ldsoff = lrow * BK + lc * 8;
    const size_t abase = (size_t)(m0 + lrow) * KDIM + cg * 8;
    const size_t bbase = (size_t)(n0 + lrow) * KDIM + cg * 8;

#define STAGE(kt, buf)                                                          \
    {                                                                           \
        _Pragma("unroll")                                                       \
        for (int s = 0; s < 4; ++s)                                             \
            async_copy16(&Abas[abase + (size_t)(32 * s) * KDIM + (kt)],         \
                         &As[buf][ldsoff + 32 * s * BK]);                       \
        _Pragma("unroll")                                                       \
        for (int s = 0; s < 4; ++s)                                             \
            async_copy16(&Wt[bbase + (size_t)(32 * s) * KDIM + (kt)],           \
                         &Bs[buf][ldsoff + 32 * s * BK]);                       \
    }

    STAGE(0, 0);
    asm volatile("s_waitcnt vmcnt(0)" ::: "memory");
    __syncthreads();

    for (int it = 0; it < KDIM / BK; ++it) {          // 60 iters
        const int buf = it & 1;
        if (it + 1 < KDIM / BK)
            STAGE((it + 1) * BK, buf ^ 1);            // prefetch into other buf

#pragma unroll
        for (int ks = 0; ks < 2; ++ks) {
            const int pc = ((ks * 4) + (lane >> 4)) ^ (lane & 7);
            bf16x8 af[4], bfr[4];
#pragma unroll
            for (int f = 0; f < 4; ++f)
                af[f]  = *(const bf16x8*)&As[buf][(wm + f * 16 + (lane & 15)) * BK + pc * 8];
#pragma unroll
            for (int f = 0; f < 4; ++f)
                bfr[f] = *(const bf16x8*)&Bs[buf][(wn + f * 16 + (lane & 15)) * BK + pc * 8];
#pragma unroll
            for (int fm = 0; fm < 4; ++fm)
#pragma unroll
                for (int fn = 0; fn < 4; ++fn)
                    acc[fm][fn] = __builtin_amdgcn_mfma_f32_16x16x32_bf16(
                        af[fm], bfr[fn], acc[fm][fn], 0, 0, 0);
        }
        asm volatile("s_waitcnt vmcnt(0)" ::: "memory");  // prefetch landed by now
        __syncthreads();
    }

    // epilogue: D mapping col=lane&15, row=(lane>>4)*4+reg  [measured m89/m91]
    const int col   = lane & 15;
    const int rbase = (lane >> 4) * 4;
#pragma unroll
    for (int fm = 0; fm < 4; ++fm) {
#pragma unroll
        for (int fn = 0; fn < 4; ++fn) {
            const int j  = n0 + wn + fn * 16 + col;
            const float bj = bias[j];
#pragma unroll
            for (int r = 0; r < 4; ++r) {
                const int row = m0 + wm + fm * 16 + rbase + r;
                out[(size_t)row * JDIM + j] = acc[fm][fn][r] + bj;
            }
        }
    }
#undef STAGE
}

// ---------------- fallback (ws too small): slow but correct ----------------

__global__ __launch_bounds__(256)
void fallback_kernel(const float* __restrict__ x,
                     const float* __restrict__ coeffs,
                     const float* __restrict__ scale,
                     const float* __restrict__ shift,
                     float* __restrict__ out) {
    __shared__ float bas[KDIM];
    const int b = blockIdx.x;
    const int t = threadIdx.x;
    for (int i = t; i < IDIM; i += 256) {
        float tv = tanhf(x[(size_t)b * IDIM + i]);
#pragma unroll
        for (int g = 0; g < GRID; ++g) {
            float d = tv - (-1.0f + 0.5f * (float)g);
            bas[g * IDIM + i] = __expf(-5.0f * d * d);
        }
    }
    __syncthreads();
#pragma unroll
    for (int jj = 0; jj < 3; ++jj) {
        const int j = t + jj * 256;
        float acc = 0.f;
        for (int i = 0; i < IDIM; ++i) {
            const float sc = scale[(size_t)i * JDIM + j];
            const float* cp = &coeffs[((size_t)i * JDIM + j) * GRID];
            float s5 = 0.f;
#pragma unroll
            for (int g = 0; g < GRID; ++g) s5 += bas[g * IDIM + i] * cp[g];
            acc += s5 * sc + shift[(size_t)i * JDIM + j];
        }
        out[(size_t)b * JDIM + j] = acc;
    }
}

// ---------------- launch ----------------

extern "C" void kernel_launch(void* const* d_in, const int* in_sizes, int n_in,
                              void* d_out, int out_size, void* d_ws, size_t ws_size,
                              hipStream_t stream) {
    const float* x      = (const float*)d_in[0];
    const float* coeffs = (const float*)d_in[1];
    const float* scale  = (const float*)d_in[2];
    const float* shift  = (const float*)d_in[3];
    float* out = (float*)d_out;

    const size_t wt_bytes   = (size_t)JDIM * KDIM * sizeof(unsigned short); // 5,898,240
    const size_t bias_off   = wt_bytes;
    const size_t bias_bytes = (size_t)JDIM * sizeof(float);
    const size_t bas_off    = bias_off + bias_bytes;
    const size_t bas_bytes  = (size_t)BATCH * KDIM * sizeof(unsigned short);
    const size_t need       = bas_off + bas_bytes;                          // ~68.8 MB

    if (ws_size >= need) {
        unsigned short* Wt   = (unsigned short*)d_ws;
        float*          bias = (float*)((char*)d_ws + bias_off);
        unsigned short* Abas = (unsigned short*)((char*)d_ws + bas_off);

        basis_kernel<<<(BATCH * (IDIM / BPT)) / 256, 256, 0, stream>>>(x, Abas);
        wtbias_kernel<<<NWT + NBIAS, 256, 0, stream>>>(coeffs, scale, shift, Wt, bias);
        kan_gemm<<<dim3(JDIM / BN, BATCH / BM), 256, 0, stream>>>(Abas, Wt, bias, out);
    } else {
        fallback_kernel<<<BATCH, 256, 0, stream>>>(x, coeffs, scale, shift, out);
    }
}